// Round 9
// baseline (249.127 us; speedup 1.0000x reference)
//
#include <hip/hip_runtime.h>

// Problem constants: B=4, R=16384, S=96
#define NRAYS 65536
#define NS    96
#define NI    95

// Output layout (FP32, outputs concatenated flat in return order):
//   composite_rgb   : [0,        196608)
//   composite_depth : [196608,   262144)
//   weights         : [262144,   6488064)
//   composite_point : [6488064,  6684672)
//   tau             : [6684672,  6750208)
#define OFF_RGB   0
#define OFF_DEPTH 196608
#define OFF_W     262144
#define OFF_PT    6488064
#define OFF_TAU   6684672

// ---------------------------------------------------------------------------
// Global depth min/max. depths are jnp.sort()ed along the sample axis by
// construction, so global min = min over rays of sample 0, global max = max
// over rays of sample 95. Max encoded as atomicMin of ~bits (depths >= 0),
// so both ws slots init 0xFFFFFFFF -> single 8-byte memset.
// ---------------------------------------------------------------------------
__global__ void depth_minmax_sorted(const float* __restrict__ deps, unsigned* ws) {
    const int t = blockIdx.x * blockDim.x + threadIdx.x;   // grid covers exactly NRAYS
    float lo = deps[(size_t)t * NS];
    float hi = deps[(size_t)t * NS + (NS - 1)];
    #pragma unroll
    for (int off = 32; off; off >>= 1) {
        lo = fminf(lo, __shfl_xor(lo, off, 64));
        hi = fmaxf(hi, __shfl_xor(hi, off, 64));
    }
    if ((threadIdx.x & 63) == 0) {
        atomicMin(&ws[0], __float_as_uint(lo));
        atomicMin(&ws[1], ~__float_as_uint(hi));   // max via inverted-bit min
    }
}

__device__ __forceinline__ float softplus_fast(float x) {
    // softplus = max(x,0) + log(1 + exp(-|x|)); __logf/__expf are single
    // v_log/v_exp instrs (~1e-6 rel err; tolerance headroom ~6x).
    return fmaxf(x, 0.0f) + __logf(1.0f + __expf(-fabsf(x)));
}

// Fire-and-forget global->LDS DMA, 16 B per active lane, dest = uniform LDS
// base + lane*16 (linear). No destination VGPRs -> cannot be sunk/remat'd.
__device__ __forceinline__ void gload_lds16(const float* gp, float* lp) {
    __builtin_amdgcn_global_load_lds(
        (const __attribute__((address_space(1))) void*)gp,
        (__attribute__((address_space(3))) void*)lp,
        16, 0, 0);
}

// 2-ray tile buffer (1536 floats = 6144 B):
//   c [0,576) | p [576,1152) | d [1152,1344) | n [1344,1536)
// Exactly 8 vmem instructions per call (the counted-vmcnt unit).
__device__ __forceinline__ void issue_dma2(const float* __restrict__ colors,
                                           const float* __restrict__ coords,
                                           const float* __restrict__ deps,
                                           const float* __restrict__ dens,
                                           int grp, float* lbuf, int lane) {
    const size_t rb0 = (size_t)grp * 2;            // first ray of the tile
    const float* cg = colors + rb0 * (NS * 3);     // 2304 B, 16-B aligned
    const float* pg = coords + rb0 * (NS * 3);
    const float* dg = deps   + rb0 * NS;           // 768 B
    const float* ng = dens   + rb0 * NS;
    gload_lds16(cg +       4 * lane, lbuf);          // c [0,256)
    gload_lds16(cg + 256 + 4 * lane, lbuf + 256);    // c [256,512)
    gload_lds16(pg +       4 * lane, lbuf + 576);    // p [0,256)
    gload_lds16(pg + 256 + 4 * lane, lbuf + 832);    // p [256,512)
    if (lane < 48) {
        gload_lds16(dg + 4 * lane, lbuf + 1152);     // d [0,192)
        gload_lds16(ng + 4 * lane, lbuf + 1344);     // n [0,192)
    }
    if (lane < 16) {
        gload_lds16(cg + 512 + 4 * lane, lbuf + 512);    // c tail [512,576)
        gload_lds16(pg + 512 + 4 * lane, lbuf + 1088);   // p tail [512,576)
    }
}

// ---------------------------------------------------------------------------
// R8 (resubmit; previous run died to an infra container failure, not the
// kernel -- source re-audited: vmcnt schedule deadlock-free, all bounds and
// alignments verified). Theory: R1-R7 factorized the space: high-TLP
// configs (R1/R4/R6, 10-20 waves/CU) have ~10-20% DMA duty cycle; the
// deep-pipelined R7 had ~100% duty but only 4 waves/CU (LDS: 24.6 KB/wave
// for a dbuf 4-ray tile). Both products land at ~1.4-1.7 TB/s delivered.
// Fix: 2-ray tiles (32 lanes/ray, 3 samples/lane) -> dbuf = 12.3 KB ->
// SINGLE-WAVE 64-thread blocks, 13 resident/CU cap, each looping 16 tiles
// with the R7-proven schedule: [wait vmcnt(8)] [consume] [stores] [dma it+2].
// The wait retires everything older than the newest 8 ops (= next tile's
// DMA): prior stores retired, current tile landed, next tile keeps flying
// -> ~100% duty at ~8-13 waves/CU ~= 48-79 KB/CU outstanding -> HBM-limited.
// Robust to store-instr merging (stores are always older than the 8).
// Bijective XCD swizzle (2048 % 8 == 0) for contiguous per-XCD streams.
// ---------------------------------------------------------------------------
__launch_bounds__(64)
__global__ void raymarch(const float* __restrict__ colors,
                         const float* __restrict__ dens,
                         const float* __restrict__ deps,
                         const float* __restrict__ coords,
                         const int* __restrict__ wbp,
                         const unsigned* __restrict__ mm,
                         float* __restrict__ out) {
    __shared__ float sbuf[2 * 1536];   // 12288 B: two 2-ray tile buffers

    const int lane = threadIdx.x;                 // single wave per block
    const int sub  = lane & 31;                   // position within ray (0..31)
    const int r2   = lane >> 5;                   // ray within tile (0..1)

    // bijective XCD swizzle: 2048 blocks, chunks of 256 per XCD
    const int blk = (blockIdx.x & 7) * 256 + (blockIdx.x >> 3);

    // prologue: fill both buffers (tiles 0 and 1)
    issue_dma2(colors, coords, deps, dens, blk * 16 + 0, sbuf,        lane);
    issue_dma2(colors, coords, deps, dens, blk * 16 + 1, sbuf + 1536, lane);

    for (int it = 0; it < 16; ++it) {
        float* lb = sbuf + (it & 1) * 1536;

        // Retire all but the newest 8 vmem ops (= next tile's DMA): prior
        // stores done, tile `it` landed, tile `it+1` stays in flight.
        if (it < 15) asm volatile("s_waitcnt vmcnt(8)" ::: "memory");
        else         asm volatile("s_waitcnt vmcnt(0)" ::: "memory");
        __builtin_amdgcn_sched_barrier(0);

        const int grp = blk * 16 + it;
        const int g   = grp * 2 + r2;             // global ray id

        // ---- per-lane slices from LDS: 3 samples/lane ----
        float d[3], n[3], c[9], p[9];
        {
            const int db = 1152 + r2 * 96 + 3 * sub;
            const int nb = 1344 + r2 * 96 + 3 * sub;
            #pragma unroll
            for (int j = 0; j < 3; ++j) { d[j] = lb[db + j]; n[j] = lb[nb + j]; }
            const int cb = r2 * 288 + 9 * sub;
            const int pb = 576 + r2 * 288 + 9 * sub;
            #pragma unroll
            for (int j = 0; j < 9; ++j) { c[j] = lb[cb + j]; p[j] = lb[pb + j]; }
        }
        // neighbor sample 3*sub+3 = next lane's sample 0 (dummy for sub 31)
        const int no3 = (sub < 31) ? 3 * (sub + 1) : 0;
        const int no9 = (sub < 31) ? 9 * (sub + 1) : 0;
        float d3  = lb[1152 + r2 * 96 + no3];
        float n3  = lb[1344 + r2 * 96 + no3];
        float cn0 = lb[r2 * 288 + no9 + 0];
        float cn1 = lb[r2 * 288 + no9 + 1];
        float cn2 = lb[r2 * 288 + no9 + 2];
        float pn0 = lb[576 + r2 * 288 + no9 + 0];
        float pn1 = lb[576 + r2 * 288 + no9 + 1];
        float pn2 = lb[576 + r2 * 288 + no9 + 2];

        // ---- per-interval alpha / transmittance factor ----
        // Lane sub owns intervals 3*sub+j, j=0..2; invalid only (sub=31,j=2).
        float a[3], f[3];
        #pragma unroll
        for (int j = 0; j < 3; ++j) {
            float dn1 = (j < 2) ? d[j+1] : d3;
            float nn1 = (j < 2) ? n[j+1] : n3;
            float E = __expf(-softplus_fast(0.5f * (n[j] + nn1)) * (dn1 - d[j]));
            const bool valid = (j < 2) || (sub < 31);   // compile-time except j==2
            a[j] = valid ? (1.0f - E) : 0.0f;
            f[j] = valid ? (E + 1e-10f) : 1.0f;
        }

        // ---- inclusive scan of per-lane factor product over 32 lanes ----
        float incl = f[0] * f[1] * f[2];
        #pragma unroll
        for (int off = 1; off < 32; off <<= 1) {
            float t = __shfl_up(incl, off, 32);
            if (sub >= off) incl *= t;
        }
        float excl = __shfl_up(incl, 1, 32);     // trans[3*sub]
        if (sub == 0) excl = 1.0f;

        // ---- weights (direct scatter, L2-merged) + composite partials ----
        float acc[8];
        #pragma unroll
        for (int k = 0; k < 8; ++k) acc[k] = 0.0f;
        float t = excl;                          // trans[3*sub + j] at top of j
        float tauc = 0.0f;
        const size_t wb = (size_t)OFF_W + (size_t)g * NI + 3 * sub;
        #pragma unroll
        for (int j = 0; j < 3; ++j) {
            float w = a[j] * t;
            if (j < 2 || sub < 31) out[wb + j] = w;      // weights output
            float dn1 = (j < 2) ? d[j+1] : d3;
            float dm  = 0.5f * (d[j] + dn1);
            float cmx = 0.5f * (c[3*j+0] + ((j < 2) ? c[3*j+3] : cn0));
            float cmy = 0.5f * (c[3*j+1] + ((j < 2) ? c[3*j+4] : cn1));
            float cmz = 0.5f * (c[3*j+2] + ((j < 2) ? c[3*j+5] : cn2));
            float pmx = 0.5f * (p[3*j+0] + ((j < 2) ? p[3*j+3] : pn0));
            float pmy = 0.5f * (p[3*j+1] + ((j < 2) ? p[3*j+4] : pn1));
            float pmz = 0.5f * (p[3*j+2] + ((j < 2) ? p[3*j+5] : pn2));
            acc[0] += w * cmx;  acc[1] += w * cmy;  acc[2] += w * cmz;
            acc[3] += w * pmx;  acc[4] += w * pmy;  acc[5] += w * pmz;
            acc[6] += w * dm;   acc[7] += w;
            if (j == 1) tauc = t;    // sub==31, j==1: t == trans[94] == tau
            t *= f[j];
        }
        float tau = __shfl(tauc, (lane & 32) | 31, 64);

        // ---- reduce 8 accumulators across the 32-lane group ----
        #pragma unroll
        for (int k = 0; k < 8; ++k) {
            #pragma unroll
            for (int off = 1; off < 32; off <<= 1)
                acc[k] += __shfl_xor(acc[k], off, 64);
        }

        if (sub == 0) {
            float add = (wbp != nullptr && wbp[0] != 0) ? (1.0f - acc[7]) : 0.0f;
            size_t rb = (size_t)OFF_RGB + (size_t)g * 3;
            out[rb + 0] = acc[0] + add;
            out[rb + 1] = acc[1] + add;
            out[rb + 2] = acc[2] + add;
            size_t pb = (size_t)OFF_PT + (size_t)g * 3;
            out[pb + 0] = acc[3];
            out[pb + 1] = acc[4];
            out[pb + 2] = acc[5];
            float cd = acc[6];
            if (cd != cd) cd = __int_as_float(0x7f800000);   // nan_to_num -> +inf
            float dmin = __uint_as_float(mm[0]);
            float dmax = __uint_as_float(~mm[1]);
            cd = fminf(fmaxf(cd, dmin), dmax);               // jnp.clip(global min/max)
            out[OFF_DEPTH + g] = cd;
            out[OFF_TAU + g]   = tau;
        }

        // ---- issue DMA two tiles ahead into the just-freed buffer ----
        if (it < 14) {
            __builtin_amdgcn_sched_barrier(0);
            issue_dma2(colors, coords, deps, dens, blk * 16 + it + 2, lb, lane);
        }
    }
}

extern "C" void kernel_launch(void* const* d_in, const int* in_sizes, int n_in,
                              void* d_out, int out_size, void* d_ws, size_t ws_size,
                              hipStream_t stream) {
    const float* colors = (const float*)d_in[0];
    const float* dens   = (const float*)d_in[1];
    const float* deps   = (const float*)d_in[2];
    const float* coords = (const float*)d_in[3];
    const int*   wb     = (n_in > 4) ? (const int*)d_in[4] : nullptr;
    float* out = (float*)d_out;
    unsigned* mm = (unsigned*)d_ws;

    // Both slots init 0xFFFFFFFF (min slot: uint-max; max slot stores ~bits).
    hipMemsetAsync(mm, 0xFF, 8, stream);
    depth_minmax_sorted<<<NRAYS / 256, 256, 0, stream>>>(deps, mm);
    // 2048 single-wave blocks x 16 tiles x 2 rays = 65536 rays
    raymarch<<<2048, 64, 0, stream>>>(colors, dens, deps, coords, wb, mm, out);
}

// Round 10
// 248.187 us; speedup vs baseline: 1.0038x; 1.0038x over previous
//
#include <hip/hip_runtime.h>

// Problem constants: B=4, R=16384, S=96
#define NRAYS 65536
#define NS    96
#define NI    95

// Output layout (FP32, outputs concatenated flat in return order):
//   composite_rgb   : [0,        196608)
//   composite_depth : [196608,   262144)
//   weights         : [262144,   6488064)
//   composite_point : [6488064,  6684672)
//   tau             : [6684672,  6750208)
#define OFF_RGB   0
#define OFF_DEPTH 196608
#define OFF_W     262144
#define OFF_PT    6488064
#define OFF_TAU   6684672

// ---------------------------------------------------------------------------
// Global depth min/max. depths are jnp.sort()ed along the sample axis by
// construction, so global min = min over rays of sample 0, global max = max
// over rays of sample 95. Max encoded as atomicMin of ~bits (depths >= 0),
// so both ws slots init 0xFFFFFFFF -> single 8-byte memset.
// ---------------------------------------------------------------------------
__global__ void depth_minmax_sorted(const float* __restrict__ deps, unsigned* ws) {
    const int t = blockIdx.x * blockDim.x + threadIdx.x;   // grid covers exactly NRAYS
    float lo = deps[(size_t)t * NS];
    float hi = deps[(size_t)t * NS + (NS - 1)];
    #pragma unroll
    for (int off = 32; off; off >>= 1) {
        lo = fminf(lo, __shfl_xor(lo, off, 64));
        hi = fmaxf(hi, __shfl_xor(hi, off, 64));
    }
    if ((threadIdx.x & 63) == 0) {
        atomicMin(&ws[0], __float_as_uint(lo));
        atomicMin(&ws[1], ~__float_as_uint(hi));   // max via inverted-bit min
    }
}

__device__ __forceinline__ float softplus_fast(float x) {
    // softplus = max(x,0) + log(1 + exp(-|x|)); __logf/__expf are single
    // v_log/v_exp instrs (~1e-6 rel err; tolerance headroom ~6x).
    return fmaxf(x, 0.0f) + __logf(1.0f + __expf(-fabsf(x)));
}

// Fire-and-forget global->LDS DMA, 16 B per active lane, dest = uniform LDS
// base + lane*16 (linear). No destination VGPRs -> cannot be sunk/remat'd.
__device__ __forceinline__ void gload_lds16(const float* gp, float* lp) {
    __builtin_amdgcn_global_load_lds(
        (const __attribute__((address_space(1))) void*)gp,
        (__attribute__((address_space(3))) void*)lp,
        16, 0, 0);
}

// 2-ray tile buffer (1536 floats = 6144 B):
//   c [0,576) | p [576,1152) | d [1152,1344) | n [1344,1536)
// Exactly 8 vmem instructions per call (the counted-vmcnt unit).
__device__ __forceinline__ void issue_dma2(const float* __restrict__ colors,
                                           const float* __restrict__ coords,
                                           const float* __restrict__ deps,
                                           const float* __restrict__ dens,
                                           int grp, float* lbuf, int lane) {
    const size_t rb0 = (size_t)grp * 2;            // first ray of the tile
    const float* cg = colors + rb0 * (NS * 3);     // 2304 B, 16-B aligned
    const float* pg = coords + rb0 * (NS * 3);
    const float* dg = deps   + rb0 * NS;           // 768 B
    const float* ng = dens   + rb0 * NS;
    gload_lds16(cg +       4 * lane, lbuf);          // c [0,256)
    gload_lds16(cg + 256 + 4 * lane, lbuf + 256);    // c [256,512)
    gload_lds16(pg +       4 * lane, lbuf + 576);    // p [0,256)
    gload_lds16(pg + 256 + 4 * lane, lbuf + 832);    // p [256,512)
    if (lane < 48) {
        gload_lds16(dg + 4 * lane, lbuf + 1152);     // d [0,192)
        gload_lds16(ng + 4 * lane, lbuf + 1344);     // n [0,192)
    }
    if (lane < 16) {
        gload_lds16(cg + 512 + 4 * lane, lbuf + 512);    // c tail [512,576)
        gload_lds16(pg + 512 + 4 * lane, lbuf + 1088);   // p tail [512,576)
    }
}

// ---------------------------------------------------------------------------
// R10: R8 with the grid arithmetic FIXED. R8's counters (occupancy 17.9% =
// ~5.7 waves/CU) exposed my error: 2048 blocks = exactly 8 blocks/CU, so
// the 13-resident LDS cap was unreachable -- the grid itself capped TLP.
// R8 therefore tested medium-TLP x 100%-duty (84 us, consistent with R7's
// low-TLP point), NOT the theory's key cell. Here: 4096 single-wave blocks
// x 8 tiles x 2 rays; 16 blocks/CU available, LDS cap 13 resident ->
// ~13 waves/CU, each with 8 KB of DMA permanently outstanding (~104 KB/CU).
// Schedule unchanged (R7/R8-proven): [wait vmcnt(8)] [consume] [stores]
// [dma it+2]; wait retires prior stores + current tile, keeps next tile
// flying. Bijective XCD swizzle: 4096 % 8 == 0, chunks of 512.
// FINAL pre-commitment: if occupancy >=30% and dur still >=70 us, the
// invariance spans TLP x duty x staging x tile x stores with no saturated
// counter -> declare ROOFLINE at the ~3 TB/s mixed-pattern demand ceiling.
// ---------------------------------------------------------------------------
__launch_bounds__(64)
__global__ void raymarch(const float* __restrict__ colors,
                         const float* __restrict__ dens,
                         const float* __restrict__ deps,
                         const float* __restrict__ coords,
                         const int* __restrict__ wbp,
                         const unsigned* __restrict__ mm,
                         float* __restrict__ out) {
    __shared__ float sbuf[2 * 1536];   // 12288 B: two 2-ray tile buffers

    const int lane = threadIdx.x;                 // single wave per block
    const int sub  = lane & 31;                   // position within ray (0..31)
    const int r2   = lane >> 5;                   // ray within tile (0..1)

    // bijective XCD swizzle: 4096 blocks, chunks of 512 per XCD
    const int blk = (blockIdx.x & 7) * 512 + (blockIdx.x >> 3);

    // prologue: fill both buffers (tiles 0 and 1)
    issue_dma2(colors, coords, deps, dens, blk * 8 + 0, sbuf,        lane);
    issue_dma2(colors, coords, deps, dens, blk * 8 + 1, sbuf + 1536, lane);

    for (int it = 0; it < 8; ++it) {
        float* lb = sbuf + (it & 1) * 1536;

        // Retire all but the newest 8 vmem ops (= next tile's DMA): prior
        // stores done, tile `it` landed, tile `it+1` stays in flight.
        if (it < 7) asm volatile("s_waitcnt vmcnt(8)" ::: "memory");
        else        asm volatile("s_waitcnt vmcnt(0)" ::: "memory");
        __builtin_amdgcn_sched_barrier(0);

        const int grp = blk * 8 + it;
        const int g   = grp * 2 + r2;             // global ray id

        // ---- per-lane slices from LDS: 3 samples/lane ----
        float d[3], n[3], c[9], p[9];
        {
            const int db = 1152 + r2 * 96 + 3 * sub;
            const int nb = 1344 + r2 * 96 + 3 * sub;
            #pragma unroll
            for (int j = 0; j < 3; ++j) { d[j] = lb[db + j]; n[j] = lb[nb + j]; }
            const int cb = r2 * 288 + 9 * sub;
            const int pb = 576 + r2 * 288 + 9 * sub;
            #pragma unroll
            for (int j = 0; j < 9; ++j) { c[j] = lb[cb + j]; p[j] = lb[pb + j]; }
        }
        // neighbor sample 3*sub+3 = next lane's sample 0 (dummy for sub 31)
        const int no3 = (sub < 31) ? 3 * (sub + 1) : 0;
        const int no9 = (sub < 31) ? 9 * (sub + 1) : 0;
        float d3  = lb[1152 + r2 * 96 + no3];
        float n3  = lb[1344 + r2 * 96 + no3];
        float cn0 = lb[r2 * 288 + no9 + 0];
        float cn1 = lb[r2 * 288 + no9 + 1];
        float cn2 = lb[r2 * 288 + no9 + 2];
        float pn0 = lb[576 + r2 * 288 + no9 + 0];
        float pn1 = lb[576 + r2 * 288 + no9 + 1];
        float pn2 = lb[576 + r2 * 288 + no9 + 2];

        // ---- per-interval alpha / transmittance factor ----
        // Lane sub owns intervals 3*sub+j, j=0..2; invalid only (sub=31,j=2).
        float a[3], f[3];
        #pragma unroll
        for (int j = 0; j < 3; ++j) {
            float dn1 = (j < 2) ? d[j+1] : d3;
            float nn1 = (j < 2) ? n[j+1] : n3;
            float E = __expf(-softplus_fast(0.5f * (n[j] + nn1)) * (dn1 - d[j]));
            const bool valid = (j < 2) || (sub < 31);   // compile-time except j==2
            a[j] = valid ? (1.0f - E) : 0.0f;
            f[j] = valid ? (E + 1e-10f) : 1.0f;
        }

        // ---- inclusive scan of per-lane factor product over 32 lanes ----
        float incl = f[0] * f[1] * f[2];
        #pragma unroll
        for (int off = 1; off < 32; off <<= 1) {
            float t = __shfl_up(incl, off, 32);
            if (sub >= off) incl *= t;
        }
        float excl = __shfl_up(incl, 1, 32);     // trans[3*sub]
        if (sub == 0) excl = 1.0f;

        // ---- weights (direct scatter, L2-merged) + composite partials ----
        float acc[8];
        #pragma unroll
        for (int k = 0; k < 8; ++k) acc[k] = 0.0f;
        float t = excl;                          // trans[3*sub + j] at top of j
        float tauc = 0.0f;
        const size_t wb = (size_t)OFF_W + (size_t)g * NI + 3 * sub;
        #pragma unroll
        for (int j = 0; j < 3; ++j) {
            float w = a[j] * t;
            if (j < 2 || sub < 31) out[wb + j] = w;      // weights output
            float dn1 = (j < 2) ? d[j+1] : d3;
            float dm  = 0.5f * (d[j] + dn1);
            float cmx = 0.5f * (c[3*j+0] + ((j < 2) ? c[3*j+3] : cn0));
            float cmy = 0.5f * (c[3*j+1] + ((j < 2) ? c[3*j+4] : cn1));
            float cmz = 0.5f * (c[3*j+2] + ((j < 2) ? c[3*j+5] : cn2));
            float pmx = 0.5f * (p[3*j+0] + ((j < 2) ? p[3*j+3] : pn0));
            float pmy = 0.5f * (p[3*j+1] + ((j < 2) ? p[3*j+4] : pn1));
            float pmz = 0.5f * (p[3*j+2] + ((j < 2) ? p[3*j+5] : pn2));
            acc[0] += w * cmx;  acc[1] += w * cmy;  acc[2] += w * cmz;
            acc[3] += w * pmx;  acc[4] += w * pmy;  acc[5] += w * pmz;
            acc[6] += w * dm;   acc[7] += w;
            if (j == 1) tauc = t;    // sub==31, j==1: t == trans[94] == tau
            t *= f[j];
        }
        float tau = __shfl(tauc, (lane & 32) | 31, 64);

        // ---- reduce 8 accumulators across the 32-lane group ----
        #pragma unroll
        for (int k = 0; k < 8; ++k) {
            #pragma unroll
            for (int off = 1; off < 32; off <<= 1)
                acc[k] += __shfl_xor(acc[k], off, 64);
        }

        if (sub == 0) {
            float add = (wbp != nullptr && wbp[0] != 0) ? (1.0f - acc[7]) : 0.0f;
            size_t rb = (size_t)OFF_RGB + (size_t)g * 3;
            out[rb + 0] = acc[0] + add;
            out[rb + 1] = acc[1] + add;
            out[rb + 2] = acc[2] + add;
            size_t pb = (size_t)OFF_PT + (size_t)g * 3;
            out[pb + 0] = acc[3];
            out[pb + 1] = acc[4];
            out[pb + 2] = acc[5];
            float cd = acc[6];
            if (cd != cd) cd = __int_as_float(0x7f800000);   // nan_to_num -> +inf
            float dmin = __uint_as_float(mm[0]);
            float dmax = __uint_as_float(~mm[1]);
            cd = fminf(fmaxf(cd, dmin), dmax);               // jnp.clip(global min/max)
            out[OFF_DEPTH + g] = cd;
            out[OFF_TAU + g]   = tau;
        }

        // ---- issue DMA two tiles ahead into the just-freed buffer ----
        if (it < 6) {
            __builtin_amdgcn_sched_barrier(0);
            issue_dma2(colors, coords, deps, dens, blk * 8 + it + 2, lb, lane);
        }
    }
}

extern "C" void kernel_launch(void* const* d_in, const int* in_sizes, int n_in,
                              void* d_out, int out_size, void* d_ws, size_t ws_size,
                              hipStream_t stream) {
    const float* colors = (const float*)d_in[0];
    const float* dens   = (const float*)d_in[1];
    const float* deps   = (const float*)d_in[2];
    const float* coords = (const float*)d_in[3];
    const int*   wb     = (n_in > 4) ? (const int*)d_in[4] : nullptr;
    float* out = (float*)d_out;
    unsigned* mm = (unsigned*)d_ws;

    // Both slots init 0xFFFFFFFF (min slot: uint-max; max slot stores ~bits).
    hipMemsetAsync(mm, 0xFF, 8, stream);
    depth_minmax_sorted<<<NRAYS / 256, 256, 0, stream>>>(deps, mm);
    // 4096 single-wave blocks x 8 tiles x 2 rays = 65536 rays
    raymarch<<<4096, 64, 0, stream>>>(colors, dens, deps, coords, wb, mm, out);
}

// Round 11
// 246.243 us; speedup vs baseline: 1.0117x; 1.0079x over previous
//
#include <hip/hip_runtime.h>

// Problem constants: B=4, R=16384, S=96
#define NRAYS 65536
#define NS    96
#define NI    95

// Output layout (FP32, outputs concatenated flat in return order):
//   composite_rgb   : [0,        196608)
//   composite_depth : [196608,   262144)
//   weights         : [262144,   6488064)
//   composite_point : [6488064,  6684672)
//   tau             : [6684672,  6750208)
#define OFF_RGB   0
#define OFF_DEPTH 196608
#define OFF_W     262144
#define OFF_PT    6488064
#define OFF_TAU   6684672

// ---------------------------------------------------------------------------
// Global depth min/max. depths are jnp.sort()ed along the sample axis by
// construction, so global min = min over rays of sample 0, global max = max
// over rays of sample 95. Max encoded as atomicMin of ~bits (depths >= 0),
// so both ws slots init 0xFFFFFFFF -> single 8-byte memset.
// ---------------------------------------------------------------------------
__global__ void depth_minmax_sorted(const float* __restrict__ deps, unsigned* ws) {
    const int t = blockIdx.x * blockDim.x + threadIdx.x;   // grid covers exactly NRAYS
    float lo = deps[(size_t)t * NS];
    float hi = deps[(size_t)t * NS + (NS - 1)];
    #pragma unroll
    for (int off = 32; off; off >>= 1) {
        lo = fminf(lo, __shfl_xor(lo, off, 64));
        hi = fmaxf(hi, __shfl_xor(hi, off, 64));
    }
    if ((threadIdx.x & 63) == 0) {
        atomicMin(&ws[0], __float_as_uint(lo));
        atomicMin(&ws[1], ~__float_as_uint(hi));   // max via inverted-bit min
    }
}

__device__ __forceinline__ float softplus_fast(float x) {
    // softplus = max(x,0) + log(1 + exp(-|x|)); __logf/__expf are single
    // v_log/v_exp instrs (~1e-6 rel err; tolerance headroom ~6x).
    return fmaxf(x, 0.0f) + __logf(1.0f + __expf(-fabsf(x)));
}

// Fire-and-forget global->LDS DMA, 16 B per active lane, dest = uniform LDS
// base + lane*16 (linear). No destination VGPRs -> cannot be sunk/remat'd.
__device__ __forceinline__ void gload_lds16(const float* gp, float* lp) {
    __builtin_amdgcn_global_load_lds(
        (const __attribute__((address_space(1))) void*)gp,
        (__attribute__((address_space(3))) void*)lp,
        16, 0, 0);
}

// 2-ray tile buffer (1536 floats = 6144 B):
//   c [0,576) | p [576,1152) | d [1152,1344) | n [1344,1536)
// Exactly 8 vmem instructions per call (the counted-vmcnt unit).
__device__ __forceinline__ void issue_dma2(const float* __restrict__ colors,
                                           const float* __restrict__ coords,
                                           const float* __restrict__ deps,
                                           const float* __restrict__ dens,
                                           int grp, float* lbuf, int lane) {
    const size_t rb0 = (size_t)grp * 2;            // first ray of the tile
    const float* cg = colors + rb0 * (NS * 3);     // 2304 B, 16-B aligned
    const float* pg = coords + rb0 * (NS * 3);
    const float* dg = deps   + rb0 * NS;           // 768 B
    const float* ng = dens   + rb0 * NS;
    gload_lds16(cg +       4 * lane, lbuf);          // c [0,256)
    gload_lds16(cg + 256 + 4 * lane, lbuf + 256);    // c [256,512)
    gload_lds16(pg +       4 * lane, lbuf + 576);    // p [0,256)
    gload_lds16(pg + 256 + 4 * lane, lbuf + 832);    // p [256,512)
    if (lane < 48) {
        gload_lds16(dg + 4 * lane, lbuf + 1152);     // d [0,192)
        gload_lds16(ng + 4 * lane, lbuf + 1344);     // n [0,192)
    }
    if (lane < 16) {
        gload_lds16(cg + 512 + 4 * lane, lbuf + 512);    // c tail [512,576)
        gload_lds16(pg + 512 + 4 * lane, lbuf + 1088);   // p tail [512,576)
    }
}

// ---------------------------------------------------------------------------
// R11: the decisive TLP x duty cell, via MULTI-WAVE persistent blocks.
// R10's counters (occupancy 24% = ~8 waves/CU despite 16 blocks/CU
// available and a 13-block LDS cap) showed single-wave workgroups hit a
// per-CU workgroup-dispatch cap -- the 12+ waves/CU x 100%-duty cell was
// STILL unvisited (pipeline series so far: 4w=87, 5.7w=84, 8w=85-88 us).
// Here: 256-thread blocks carrying 4 INDEPENDENT pipelined waves (wave-
// private dbuf pairs, no barriers -- R7-proven), LDS 49152 B -> 3 blocks/CU
// = 12 resident waves/CU from only 3 workgroups. Grid 1024 (4/CU available
// > 3 cap), 8 tiles/wave. Schedule and value path identical to verified
// R10: [wait vmcnt(8)] [consume] [stores] [dma it+2]; bijective XCD
// swizzle (1024 % 8 == 0, chunks of 128).
// BINDING pre-commitment: occupancy >=~11 waves/CU and dur >= 70 us
// -> declare ROOFLINE (design space fully swept, <±10% sensitivity).
// ---------------------------------------------------------------------------
__launch_bounds__(256)
__global__ void raymarch(const float* __restrict__ colors,
                         const float* __restrict__ dens,
                         const float* __restrict__ deps,
                         const float* __restrict__ coords,
                         const int* __restrict__ wbp,
                         const unsigned* __restrict__ mm,
                         float* __restrict__ out) {
    __shared__ float sbuf[4 * 2 * 1536];   // 49152 B: 4 waves x dbuf pair

    const int tid  = threadIdx.x;
    const int lane = tid & 63;
    const int wv   = tid >> 6;                    // wave in block (0..3)
    const int sub  = lane & 31;                   // position within ray (0..31)
    const int r2   = lane >> 5;                   // ray within tile (0..1)

    // bijective XCD swizzle: 1024 blocks, chunks of 128 per XCD
    const int blk = (blockIdx.x & 7) * 128 + (blockIdx.x >> 3);

    float* wreg = sbuf + wv * 3072;               // this wave's dbuf pair

    // Each wave processes 8 tiles: grp = blk*32 + it*4 + wv
    // prologue: fill both buffers (tiles it=0 and it=1)
    issue_dma2(colors, coords, deps, dens, blk * 32 + 0 * 4 + wv, wreg,        lane);
    issue_dma2(colors, coords, deps, dens, blk * 32 + 1 * 4 + wv, wreg + 1536, lane);

    for (int it = 0; it < 8; ++it) {
        float* lb = wreg + (it & 1) * 1536;

        // Retire all but the newest 8 vmem ops (= next tile's DMA): prior
        // stores done, tile `it` landed, tile `it+1` stays in flight.
        if (it < 7) asm volatile("s_waitcnt vmcnt(8)" ::: "memory");
        else        asm volatile("s_waitcnt vmcnt(0)" ::: "memory");
        __builtin_amdgcn_sched_barrier(0);

        const int grp = blk * 32 + it * 4 + wv;
        const int g   = grp * 2 + r2;             // global ray id

        // ---- per-lane slices from LDS: 3 samples/lane ----
        float d[3], n[3], c[9], p[9];
        {
            const int db = 1152 + r2 * 96 + 3 * sub;
            const int nb = 1344 + r2 * 96 + 3 * sub;
            #pragma unroll
            for (int j = 0; j < 3; ++j) { d[j] = lb[db + j]; n[j] = lb[nb + j]; }
            const int cb = r2 * 288 + 9 * sub;
            const int pb = 576 + r2 * 288 + 9 * sub;
            #pragma unroll
            for (int j = 0; j < 9; ++j) { c[j] = lb[cb + j]; p[j] = lb[pb + j]; }
        }
        // neighbor sample 3*sub+3 = next lane's sample 0 (dummy for sub 31)
        const int no3 = (sub < 31) ? 3 * (sub + 1) : 0;
        const int no9 = (sub < 31) ? 9 * (sub + 1) : 0;
        float d3  = lb[1152 + r2 * 96 + no3];
        float n3  = lb[1344 + r2 * 96 + no3];
        float cn0 = lb[r2 * 288 + no9 + 0];
        float cn1 = lb[r2 * 288 + no9 + 1];
        float cn2 = lb[r2 * 288 + no9 + 2];
        float pn0 = lb[576 + r2 * 288 + no9 + 0];
        float pn1 = lb[576 + r2 * 288 + no9 + 1];
        float pn2 = lb[576 + r2 * 288 + no9 + 2];

        // ---- per-interval alpha / transmittance factor ----
        // Lane sub owns intervals 3*sub+j, j=0..2; invalid only (sub=31,j=2).
        float a[3], f[3];
        #pragma unroll
        for (int j = 0; j < 3; ++j) {
            float dn1 = (j < 2) ? d[j+1] : d3;
            float nn1 = (j < 2) ? n[j+1] : n3;
            float E = __expf(-softplus_fast(0.5f * (n[j] + nn1)) * (dn1 - d[j]));
            const bool valid = (j < 2) || (sub < 31);   // compile-time except j==2
            a[j] = valid ? (1.0f - E) : 0.0f;
            f[j] = valid ? (E + 1e-10f) : 1.0f;
        }

        // ---- inclusive scan of per-lane factor product over 32 lanes ----
        float incl = f[0] * f[1] * f[2];
        #pragma unroll
        for (int off = 1; off < 32; off <<= 1) {
            float t = __shfl_up(incl, off, 32);
            if (sub >= off) incl *= t;
        }
        float excl = __shfl_up(incl, 1, 32);     // trans[3*sub]
        if (sub == 0) excl = 1.0f;

        // ---- weights (direct scatter, L2-merged) + composite partials ----
        float acc[8];
        #pragma unroll
        for (int k = 0; k < 8; ++k) acc[k] = 0.0f;
        float t = excl;                          // trans[3*sub + j] at top of j
        float tauc = 0.0f;
        const size_t wb = (size_t)OFF_W + (size_t)g * NI + 3 * sub;
        #pragma unroll
        for (int j = 0; j < 3; ++j) {
            float w = a[j] * t;
            if (j < 2 || sub < 31) out[wb + j] = w;      // weights output
            float dn1 = (j < 2) ? d[j+1] : d3;
            float dm  = 0.5f * (d[j] + dn1);
            float cmx = 0.5f * (c[3*j+0] + ((j < 2) ? c[3*j+3] : cn0));
            float cmy = 0.5f * (c[3*j+1] + ((j < 2) ? c[3*j+4] : cn1));
            float cmz = 0.5f * (c[3*j+2] + ((j < 2) ? c[3*j+5] : cn2));
            float pmx = 0.5f * (p[3*j+0] + ((j < 2) ? p[3*j+3] : pn0));
            float pmy = 0.5f * (p[3*j+1] + ((j < 2) ? p[3*j+4] : pn1));
            float pmz = 0.5f * (p[3*j+2] + ((j < 2) ? p[3*j+5] : pn2));
            acc[0] += w * cmx;  acc[1] += w * cmy;  acc[2] += w * cmz;
            acc[3] += w * pmx;  acc[4] += w * pmy;  acc[5] += w * pmz;
            acc[6] += w * dm;   acc[7] += w;
            if (j == 1) tauc = t;    // sub==31, j==1: t == trans[94] == tau
            t *= f[j];
        }
        float tau = __shfl(tauc, (lane & 32) | 31, 64);

        // ---- reduce 8 accumulators across the 32-lane group ----
        #pragma unroll
        for (int k = 0; k < 8; ++k) {
            #pragma unroll
            for (int off = 1; off < 32; off <<= 1)
                acc[k] += __shfl_xor(acc[k], off, 64);
        }

        if (sub == 0) {
            float add = (wbp != nullptr && wbp[0] != 0) ? (1.0f - acc[7]) : 0.0f;
            size_t rb = (size_t)OFF_RGB + (size_t)g * 3;
            out[rb + 0] = acc[0] + add;
            out[rb + 1] = acc[1] + add;
            out[rb + 2] = acc[2] + add;
            size_t pb = (size_t)OFF_PT + (size_t)g * 3;
            out[pb + 0] = acc[3];
            out[pb + 1] = acc[4];
            out[pb + 2] = acc[5];
            float cd = acc[6];
            if (cd != cd) cd = __int_as_float(0x7f800000);   // nan_to_num -> +inf
            float dmin = __uint_as_float(mm[0]);
            float dmax = __uint_as_float(~mm[1]);
            cd = fminf(fmaxf(cd, dmin), dmax);               // jnp.clip(global min/max)
            out[OFF_DEPTH + g] = cd;
            out[OFF_TAU + g]   = tau;
        }

        // ---- issue DMA two tiles ahead into the just-freed buffer ----
        if (it < 6) {
            __builtin_amdgcn_sched_barrier(0);
            issue_dma2(colors, coords, deps, dens, blk * 32 + (it + 2) * 4 + wv, lb, lane);
        }
    }
}

extern "C" void kernel_launch(void* const* d_in, const int* in_sizes, int n_in,
                              void* d_out, int out_size, void* d_ws, size_t ws_size,
                              hipStream_t stream) {
    const float* colors = (const float*)d_in[0];
    const float* dens   = (const float*)d_in[1];
    const float* deps   = (const float*)d_in[2];
    const float* coords = (const float*)d_in[3];
    const int*   wb     = (n_in > 4) ? (const int*)d_in[4] : nullptr;
    float* out = (float*)d_out;
    unsigned* mm = (unsigned*)d_ws;

    // Both slots init 0xFFFFFFFF (min slot: uint-max; max slot stores ~bits).
    hipMemsetAsync(mm, 0xFF, 8, stream);
    depth_minmax_sorted<<<NRAYS / 256, 256, 0, stream>>>(deps, mm);
    // 1024 blocks x 4 waves x 8 tiles x 2 rays = 65536 rays
    raymarch<<<1024, 256, 0, stream>>>(colors, dens, deps, coords, wb, mm, out);
}

// Round 12
// 234.344 us; speedup vs baseline: 1.0631x; 1.0508x over previous
//
#include <hip/hip_runtime.h>

// Problem constants: B=4, R=16384, S=96
#define NRAYS 65536
#define NS    96
#define NI    95

// Output layout (FP32, outputs concatenated flat in return order):
//   composite_rgb   : [0,        196608)
//   composite_depth : [196608,   262144)
//   weights         : [262144,   6488064)
//   composite_point : [6488064,  6684672)
//   tau             : [6684672,  6750208)
#define OFF_RGB   0
#define OFF_DEPTH 196608
#define OFF_W     262144
#define OFF_PT    6488064
#define OFF_TAU   6684672

// ---------------------------------------------------------------------------
// Global depth min/max. depths are jnp.sort()ed along the sample axis by
// construction, so global min = min over rays of sample 0, global max = max
// over rays of sample 95. Max encoded as atomicMin of ~bits (depths >= 0),
// so both ws slots init 0xFFFFFFFF -> single 8-byte memset.
// ---------------------------------------------------------------------------
__global__ void depth_minmax_sorted(const float* __restrict__ deps, unsigned* ws) {
    const int t = blockIdx.x * blockDim.x + threadIdx.x;   // grid covers exactly NRAYS
    float lo = deps[(size_t)t * NS];
    float hi = deps[(size_t)t * NS + (NS - 1)];
    #pragma unroll
    for (int off = 32; off; off >>= 1) {
        lo = fminf(lo, __shfl_xor(lo, off, 64));
        hi = fmaxf(hi, __shfl_xor(hi, off, 64));
    }
    if ((threadIdx.x & 63) == 0) {
        atomicMin(&ws[0], __float_as_uint(lo));
        atomicMin(&ws[1], ~__float_as_uint(hi));   // max via inverted-bit min
    }
}

__device__ __forceinline__ float softplus_fast(float x) {
    // softplus = max(x,0) + log(1 + exp(-|x|)); __logf/__expf are single
    // v_log/v_exp instrs (~1e-6 rel err; tolerance headroom ~6x).
    return fmaxf(x, 0.0f) + __logf(1.0f + __expf(-fabsf(x)));
}

// ---------------------------------------------------------------------------
// REVERT-TO-BEST (R1 kernel, 73.5 us median raymarch — fastest of 11 rounds).
// R11 post-mortem: demand-bytes/time is ~3.1 TB/s across ALL structures
// (R1-R11: transactions varied 9x, TLP 5x, DMA duty 7x — invariant). m13's
// "6.3 TB/s achievable" is a COPY (read+write summed): read-direction
// achievable ~= 3.15 TB/s. This workload reads 201 MB (88% of traffic) ->
// floor = 201/3.15 ~= 64 us + ~4 us minmax = ~70 us; best measured 73.5.
// We are ON the read-bandwidth roofline; no counter flags it because
// fabric read-BW isn't an SQ/TCC counter and L3-resident inputs hide it
// from FETCH_SIZE. 16 lanes/ray, direct consumer-layout float2 loads.
// ---------------------------------------------------------------------------
__launch_bounds__(256)
__global__ void raymarch(const float* __restrict__ colors,
                         const float* __restrict__ dens,
                         const float* __restrict__ deps,
                         const float* __restrict__ coords,
                         const int* __restrict__ wbp,
                         const unsigned* __restrict__ mm,
                         float* __restrict__ out) {
    const int lane = threadIdx.x & 63;
    const int sub  = lane & 15;                      // position within ray group
    const int g    = blockIdx.x * 16 + (threadIdx.x >> 4);   // ray id

    // ---- loads: 6 samples per lane, all float2 (aligned: stride 24 B) ----
    float d[6], n[6], c[18], p[18];
    {
        const float2* q = (const float2*)(deps + (size_t)g * NS) + 3 * sub;
        #pragma unroll
        for (int j = 0; j < 3; ++j) { float2 v = q[j]; d[2*j] = v.x; d[2*j+1] = v.y; }
    }
    {
        const float2* q = (const float2*)(dens + (size_t)g * NS) + 3 * sub;
        #pragma unroll
        for (int j = 0; j < 3; ++j) { float2 v = q[j]; n[2*j] = v.x; n[2*j+1] = v.y; }
    }
    {
        const float2* q = (const float2*)(colors + (size_t)g * NS * 3) + 9 * sub;
        #pragma unroll
        for (int j = 0; j < 9; ++j) { float2 v = q[j]; c[2*j] = v.x; c[2*j+1] = v.y; }
    }
    {
        const float2* q = (const float2*)(coords + (size_t)g * NS * 3) + 9 * sub;
        #pragma unroll
        for (int j = 0; j < 9; ++j) { float2 v = q[j]; p[2*j] = v.x; p[2*j+1] = v.y; }
    }

    // ---- neighbor sample (6*sub+6) = next lane's sample 0 (8 shuffles) ----
    const int nsrc = (lane & 48) | ((sub + 1) & 15);   // sub15 reads sub0: unused
    float d6  = __shfl(d[0], nsrc, 64);
    float n6  = __shfl(n[0], nsrc, 64);
    float cn0 = __shfl(c[0], nsrc, 64);
    float cn1 = __shfl(c[1], nsrc, 64);
    float cn2 = __shfl(c[2], nsrc, 64);
    float pn0 = __shfl(p[0], nsrc, 64);
    float pn1 = __shfl(p[1], nsrc, 64);
    float pn2 = __shfl(p[2], nsrc, 64);

    // ---- per-interval alpha / transmittance factor (interval 95 invalid) ----
    float a[6], f[6];
    #pragma unroll
    for (int i = 0; i < 6; ++i) {
        float dn1 = (i < 5) ? d[i+1] : d6;
        float nn1 = (i < 5) ? n[i+1] : n6;
        float E = __expf(-softplus_fast(0.5f * (n[i] + nn1)) * (dn1 - d[i]));
        const bool valid = (i < 5) || (sub < 15);    // compile-time except i==5
        a[i] = valid ? (1.0f - E) : 0.0f;
        f[i] = valid ? (E + 1e-10f) : 1.0f;
    }

    // ---- inclusive scan of per-lane factor product over the 16-lane group ----
    float incl = ((f[0] * f[1]) * (f[2] * f[3])) * (f[4] * f[5]);
    #pragma unroll
    for (int off = 1; off < 16; off <<= 1) {
        float t = __shfl_up(incl, off, 16);
        if (sub >= off) incl *= t;
    }
    float excl = __shfl_up(incl, 1, 16);
    if (sub == 0) excl = 1.0f;

    // ---- weights + composite partial sums (sequential within lane) ----
    float acc[8];
    #pragma unroll
    for (int k = 0; k < 8; ++k) acc[k] = 0.0f;
    float t = excl;          // t == trans[6*sub + i] at top of iteration i
    float tauc = 0.0f;
    const size_t wb = (size_t)OFF_W + (size_t)g * NI + 6 * sub;
    #pragma unroll
    for (int i = 0; i < 6; ++i) {
        float w = a[i] * t;
        if (i < 5 || sub < 15) out[wb + i] = w;      // weights output
        float dn1 = (i < 5) ? d[i+1] : d6;
        float dm  = 0.5f * (d[i] + dn1);
        float cmx = 0.5f * (c[3*i+0] + ((i < 5) ? c[3*i+3] : cn0));
        float cmy = 0.5f * (c[3*i+1] + ((i < 5) ? c[3*i+4] : cn1));
        float cmz = 0.5f * (c[3*i+2] + ((i < 5) ? c[3*i+5] : cn2));
        float pmx = 0.5f * (p[3*i+0] + ((i < 5) ? p[3*i+3] : pn0));
        float pmy = 0.5f * (p[3*i+1] + ((i < 5) ? p[3*i+4] : pn1));
        float pmz = 0.5f * (p[3*i+2] + ((i < 5) ? p[3*i+5] : pn2));
        acc[0] += w * cmx;  acc[1] += w * cmy;  acc[2] += w * cmz;
        acc[3] += w * pmx;  acc[4] += w * pmy;  acc[5] += w * pmz;
        acc[6] += w * dm;   acc[7] += w;
        if (i == 4) tauc = t;      // lane sub==15, i==4: t == trans[94] == tau
        t *= f[i];
    }
    float tau = __shfl(tauc, (lane & 48) | 15, 64);

    // ---- reduce 8 accumulators across the 16-lane group (4 butterfly steps) ----
    #pragma unroll
    for (int k = 0; k < 8; ++k) {
        #pragma unroll
        for (int off = 1; off < 16; off <<= 1)
            acc[k] += __shfl_xor(acc[k], off, 64);
    }

    if (sub == 0) {
        float add = (wbp != nullptr && wbp[0] != 0) ? (1.0f - acc[7]) : 0.0f;
        size_t rb = (size_t)OFF_RGB + (size_t)g * 3;
        out[rb + 0] = acc[0] + add;
        out[rb + 1] = acc[1] + add;
        out[rb + 2] = acc[2] + add;
        size_t pb = (size_t)OFF_PT + (size_t)g * 3;
        out[pb + 0] = acc[3];
        out[pb + 1] = acc[4];
        out[pb + 2] = acc[5];
        float cd = acc[6];
        if (cd != cd) cd = __int_as_float(0x7f800000);   // nan_to_num -> +inf
        float dmin = __uint_as_float(mm[0]);
        float dmax = __uint_as_float(~mm[1]);
        cd = fminf(fmaxf(cd, dmin), dmax);               // jnp.clip(global min/max)
        out[OFF_DEPTH + g] = cd;
        out[OFF_TAU + g]   = tau;
    }
}

extern "C" void kernel_launch(void* const* d_in, const int* in_sizes, int n_in,
                              void* d_out, int out_size, void* d_ws, size_t ws_size,
                              hipStream_t stream) {
    const float* colors = (const float*)d_in[0];
    const float* dens   = (const float*)d_in[1];
    const float* deps   = (const float*)d_in[2];
    const float* coords = (const float*)d_in[3];
    const int*   wb     = (n_in > 4) ? (const int*)d_in[4] : nullptr;
    float* out = (float*)d_out;
    unsigned* mm = (unsigned*)d_ws;

    // Both slots init 0xFFFFFFFF (min slot: uint-max; max slot stores ~bits).
    hipMemsetAsync(mm, 0xFF, 8, stream);
    depth_minmax_sorted<<<NRAYS / 256, 256, 0, stream>>>(deps, mm);
    raymarch<<<NRAYS / 16, 256, 0, stream>>>(colors, dens, deps, coords, wb, mm, out);
}